// Round 11
// baseline (191.817 us; speedup 1.0000x reference)
//
#include <hip/hip_runtime.h>
#include <hip/hip_fp16.h>

#define N_NODES 100000
#define N_EDGES 1600000
#define IN_DIM 128
#define OUT_DIM 64

#define PROJ_BLKS 782  // ceil(N_NODES/128): 128 rows per block (8 waves x 16)

// Buckets of 128 nodes: bucket = dst >> 7.
#define NB2 782        // ceil(N_NODES/128)
#define MAXB2 2560     // Binom(1.6M,128/1e5): mean 2048, sigma 45; +11 sigma
#define CUR_STRIDE 16  // one cursor per 64B line (no cross-XCD false sharing)

#define BIN_NBLK 500
#define BIN_CHUNK 3200    // BIN_NBLK * BIN_CHUNK == N_EDGES
#define BIN_THREADS 1024  // ~2 blocks/CU now (was <1/CU at 250 blocks)

#define SG_THREADS 512  // 8 waves; ~33KB LDS

typedef short short8 __attribute__((ext_vector_type(8)));
typedef float f32x4 __attribute__((ext_vector_type(4)));

__device__ __forceinline__ short bf16_trunc(float x) {
  return (short)(__float_as_uint(x) >> 16);
}
__device__ __forceinline__ float bf16_tof(short s) {
  return __uint_as_float(((unsigned)(unsigned short)s) << 16);
}
__device__ __forceinline__ float edge_ex(float p) {
  float t2 = __expf(2.f * p);
  float th = 1.f - 2.f * __builtin_amdgcn_rcpf(t2 + 1.f);
  return __expf(th);
}

// ---------------- Kernel 1: MFMA projection (R10-verified) ----------------
__global__ __launch_bounds__(512) void fat1_kernel(
    const float* __restrict__ h_init, const float* __restrict__ W1,
    const float* __restrict__ a, __half* __restrict__ h16,
    float* __restrict__ ha) {
  __shared__ short whi[16 * 64 * 8];  // 16 KB
  __shared__ short wlo[16 * 64 * 8];  // 16 KB
  int t = threadIdx.x;

  // stage W as bf16 hi/lo B-fragments (frag f=kc*4+ot, B[k][n]=W1[ot*16+n][k])
  for (int idx = t; idx < 16 * 64; idx += 512) {
    int f = idx >> 6;
    int l = idx & 63;
    int kc = f >> 2, ot = f & 3;
    const float* wsrc =
        W1 + (ot * 16 + (l & 15)) * IN_DIM + kc * 32 + (l >> 4) * 8;
    short hi[8], lo[8];
#pragma unroll
    for (int j = 0; j < 8; j++) {
      float x = wsrc[j];
      short hv = bf16_trunc(x);
      hi[j] = hv;
      lo[j] = bf16_trunc(x - bf16_tof(hv));
    }
    *(short8*)&whi[idx * 8] = *(const short8*)hi;
    *(short8*)&wlo[idx * 8] = *(const short8*)lo;
  }

  int row0 = blockIdx.x * 128;
  int w = t >> 6;  // wave 0..7, 16 rows each
  int l = t & 63;
  int m = l & 15;
  int q = l >> 4;

  int arow = row0 + w * 16 + m;
  if (arow >= N_NODES) arow = N_NODES - 1;
  const float* xsrc = h_init + (size_t)arow * IN_DIM + q * 8;

  short8 ahi[4], alo[4];
#pragma unroll
  for (int kc = 0; kc < 4; kc++) {
    float xv[8];
    *(float4*)&xv[0] = *(const float4*)(xsrc + kc * 32);
    *(float4*)&xv[4] = *(const float4*)(xsrc + kc * 32 + 4);
    short hi[8], lo[8];
#pragma unroll
    for (int j = 0; j < 8; j++) {
      short hv = bf16_trunc(xv[j]);
      hi[j] = hv;
      lo[j] = bf16_trunc(xv[j] - bf16_tof(hv));
    }
    ahi[kc] = *(const short8*)hi;
    alo[kc] = *(const short8*)lo;
  }
  __syncthreads();

  f32x4 acc[4] = {{0.f, 0.f, 0.f, 0.f},
                  {0.f, 0.f, 0.f, 0.f},
                  {0.f, 0.f, 0.f, 0.f},
                  {0.f, 0.f, 0.f, 0.f}};

#pragma unroll
  for (int kc = 0; kc < 4; kc++) {
#pragma unroll
    for (int ot = 0; ot < 4; ot++) {
      int base = (((kc << 2) | ot) * 64 + l) * 8;
      short8 bhi = *(const short8*)&whi[base];
      short8 blo = *(const short8*)&wlo[base];
      acc[ot] = __builtin_amdgcn_mfma_f32_16x16x32_bf16(ahi[kc], bhi, acc[ot],
                                                        0, 0, 0);
      acc[ot] = __builtin_amdgcn_mfma_f32_16x16x32_bf16(ahi[kc], blo, acc[ot],
                                                        0, 0, 0);
      acc[ot] = __builtin_amdgcn_mfma_f32_16x16x32_bf16(alo[kc], bhi, acc[ot],
                                                        0, 0, 0);
    }
  }

  float pa[4] = {0.f, 0.f, 0.f, 0.f};
#pragma unroll
  for (int ot = 0; ot < 4; ot++) {
    float aval = a[ot * 16 + m];
#pragma unroll
    for (int r = 0; r < 4; r++) pa[r] += acc[ot][r] * aval;
  }
  int rowb = row0 + w * 16 + q * 4;
#pragma unroll
  for (int r = 0; r < 4; r++) {
    int row = rowb + r;
    if (row < N_NODES) {
#pragma unroll
      for (int ot = 0; ot < 4; ot++)
        h16[(size_t)row * OUT_DIM + ot * 16 + m] = __float2half(acc[ot][r]);
    }
  }
#pragma unroll
  for (int r = 0; r < 4; r++) {
    pa[r] += __shfl_xor(pa[r], 1);
    pa[r] += __shfl_xor(pa[r], 2);
    pa[r] += __shfl_xor(pa[r], 4);
    pa[r] += __shfl_xor(pa[r], 8);
  }
  if (m == 0) {
#pragma unroll
    for (int r = 0; r < 4; r++) {
      int row = rowb + r;
      if (row < N_NODES) ha[row] = pa[r];
    }
  }
}

// ------- Partition into static 128-node bucket regions (R5/R8 structure) ---
// 500 blocks (~2/CU) instead of 250 (<1/CU): 2x TLP on the latency chains.
__global__ __launch_bounds__(BIN_THREADS) void bin_scatter_kernel(
    const int* __restrict__ src, const int* __restrict__ dst,
    int* __restrict__ bucket_cursor, unsigned int* __restrict__ pairs) {
  __shared__ int hst[NB2];
  __shared__ int cur[NB2];
  __shared__ int dlds[BIN_CHUNK];  // 12.8 KB dst cache
  int t = threadIdx.x;
  for (int i = t; i < NB2; i += BIN_THREADS) hst[i] = 0;
  __syncthreads();
  int beg = blockIdx.x * BIN_CHUNK;
  for (int e = t; e < BIN_CHUNK; e += BIN_THREADS) {
    int d = dst[beg + e];
    dlds[e] = d;
    atomicAdd(&hst[d >> 7], 1);
  }
  __syncthreads();
  for (int i = t; i < NB2; i += BIN_THREADS) {
    int c = hst[i];
    cur[i] =
        (c > 0) ? atomicAdd(&bucket_cursor[i * CUR_STRIDE], c) + i * MAXB2 : 0;
  }
  __syncthreads();
  for (int e = t; e < BIN_CHUNK; e += BIN_THREADS) {
    int d = dlds[e];
    int pos = atomicAdd(&cur[d >> 7], 1);
    pairs[pos] = ((unsigned int)src[beg + e] << 7) | (unsigned int)(d & 127);
  }
}

// ---- Fused sort+gather: in-LDS counting sort, then SUBGROUP-PER-NODE ------
// R10 body + two MLP-depth fixes: ex-scatter prefetches 4 edges (plds + ha)
// before the dependent edge_ex/atomic/write chain; gather runs 8 edges in
// flight (2 dependent rounds per node instead of 4).
__global__ __launch_bounds__(SG_THREADS) void sortgather_kernel(
    const __half* __restrict__ h16, const float* __restrict__ ha,
    const int* __restrict__ bucket_cursor,
    const unsigned int* __restrict__ pairs, float* __restrict__ out) {
  __shared__ unsigned int plds[MAXB2];  // 10.2 KB
  __shared__ int2 slds[MAXB2];          // 20.5 KB
  __shared__ float had[128];
  __shared__ int hist[128];
  __shared__ int scn[128];
  __shared__ int cur[128];
  __shared__ int wsum;
  int b = blockIdx.x;
  int t = threadIdx.x;
  int node0 = b << 7;
  int cnt = min(bucket_cursor[b * CUR_STRIDE], MAXB2);

  if (t < 128) {
    int node = node0 + t;
    had[t] = (node < N_NODES) ? ha[node] : 0.f;
    hist[t] = 0;
  }
  __syncthreads();
  // ingest: uint4 (4 edges/load), scalar tail
  int c4 = cnt & ~3;
  for (int i = t * 4; i < c4; i += SG_THREADS * 4) {
    uint4 p4 = *(const uint4*)&pairs[(size_t)b * MAXB2 + i];
    *(uint4*)&plds[i] = p4;
    atomicAdd(&hist[p4.x & 127u], 1);
    atomicAdd(&hist[p4.y & 127u], 1);
    atomicAdd(&hist[p4.z & 127u], 1);
    atomicAdd(&hist[p4.w & 127u], 1);
  }
  for (int i = c4 + t; i < cnt; i += SG_THREADS) {
    unsigned int p = pairs[(size_t)b * MAXB2 + i];
    plds[i] = p;
    atomicAdd(&hist[p & 127u], 1);
  }
  __syncthreads();
  // 2-wave shfl inclusive scan over hist[0..127]
  int v = (t < 128) ? hist[t] : 0;
  int x = v;
#pragma unroll
  for (int off = 1; off < 64; off <<= 1) {
    int y = __shfl_up(x, off, 64);
    if ((t & 63) >= off) x += y;
  }
  if (t == 63) wsum = x;
  __syncthreads();
  if (t >= 64 && t < 128) x += wsum;
  if (t < 128) {
    scn[t] = x;
    cur[t] = x - v;  // exclusive prefix
  }
  __syncthreads();
  // ex-scatter, 4-deep: prefetch plds + ha before the dependent chain
  for (int i0 = t; i0 < cnt; i0 += SG_THREADS * 4) {
    unsigned int pv[4];
    float hs[4];
    int nv = 0;
#pragma unroll
    for (int k = 0; k < 4; k++) {
      int i = i0 + k * SG_THREADS;
      if (i < cnt) {
        pv[k] = plds[i];
        nv = k + 1;
      }
    }
#pragma unroll
    for (int k = 0; k < 4; k++)
      if (k < nv) hs[k] = ha[pv[k] >> 7];
#pragma unroll
    for (int k = 0; k < 4; k++) {
      if (k < nv) {
        int nl = (int)(pv[k] & 127u);
        float ex = edge_ex(had[nl] - hs[k]);
        int pos = atomicAdd(&cur[nl], 1);
        slds[pos] = make_int2((int)(pv[k] & 0xFFFFFF80u), __float_as_int(ex));
      }
    }
  }
  __syncthreads();

  // ---- gather: subgroup sg (8 lanes) owns nodes sg, sg+64; 8 edges deep ---
  int sg = t >> 3;  // subgroup 0..63
  int l8 = t & 7;   // cols [8*l8, 8*l8+8)
  const char* h16b = (const char*)h16;
  float4* o4 = (float4*)out;

  for (int nl = sg; nl < 128; nl += 64) {
    int node = node0 + nl;
    if (node >= N_NODES) continue;  // only trims the last bucket
    int endp = scn[nl];
    int begp = endp - hist[nl];
    union {
      uint4 u;
      __half hh[8];
    } HD;
    HD.u = *(const uint4*)(h16b + ((size_t)node << 7) + (l8 << 4));
    float acc[8] = {0.f, 0.f, 0.f, 0.f, 0.f, 0.f, 0.f, 0.f};
    float den = 0.f;
    int last = endp - 1;

    for (int base = begp; base < endp; base += 8) {  // 8 edges in flight
      int2 e[8];
      float exv[8];
#pragma unroll
      for (int k = 0; k < 8; k++) {
        int i = base + k;
        e[k] = slds[i < endp ? i : last];
        exv[k] = (i < endp) ? __int_as_float(e[k].y) : 0.f;
      }
      uint4 uv[8];
#pragma unroll
      for (int k = 0; k < 8; k++)
        uv[k] = *(const uint4*)(h16b + e[k].x + (l8 << 4));
#pragma unroll
      for (int k = 0; k < 8; k++) {
        union {
          uint4 u;
          __half hh[8];
        } U;
        U.u = uv[k];
        float ex = exv[k];
        den += ex;
#pragma unroll
        for (int j = 0; j < 8; j++)
          acc[j] = fmaf(__half2float(U.hh[j]), ex, acc[j]);  // v_fma_mix_f32
      }
    }

    bool has = den > 0.f;
    float inv = has ? __builtin_amdgcn_rcpf(den) : 0.f;
    float hd[8];
#pragma unroll
    for (int j = 0; j < 8; j++) hd[j] = __half2float(HD.hh[j]);
    float4 r0, r1;
    r0.x = fmaxf(has ? 2.f * hd[0] - acc[0] * inv : hd[0], 0.f);
    r0.y = fmaxf(has ? 2.f * hd[1] - acc[1] * inv : hd[1], 0.f);
    r0.z = fmaxf(has ? 2.f * hd[2] - acc[2] * inv : hd[2], 0.f);
    r0.w = fmaxf(has ? 2.f * hd[3] - acc[3] * inv : hd[3], 0.f);
    r1.x = fmaxf(has ? 2.f * hd[4] - acc[4] * inv : hd[4], 0.f);
    r1.y = fmaxf(has ? 2.f * hd[5] - acc[5] * inv : hd[5], 0.f);
    r1.z = fmaxf(has ? 2.f * hd[6] - acc[6] * inv : hd[6], 0.f);
    r1.w = fmaxf(has ? 2.f * hd[7] - acc[7] * inv : hd[7], 0.f);
    o4[(size_t)node * (OUT_DIM / 4) + l8 * 2] = r0;
    o4[(size_t)node * (OUT_DIM / 4) + l8 * 2 + 1] = r1;
  }
}

extern "C" void kernel_launch(void* const* d_in, const int* in_sizes, int n_in,
                              void* d_out, int out_size, void* d_ws,
                              size_t ws_size, hipStream_t stream) {
  const float* h_init = (const float*)d_in[0];
  const float* W1 = (const float*)d_in[1];
  const float* a = (const float*)d_in[2];
  const int* src = (const int*)d_in[3];
  const int* dst = (const int*)d_in[4];
  float* out = (float*)d_out;

  // workspace layout (~22 MB)
  __half* h16 = (__half*)d_ws;                               // 12.8 MB
  float* ha = (float*)(h16 + (size_t)N_NODES * OUT_DIM);     // 0.4 MB
  unsigned int* pairs = (unsigned int*)(ha + N_NODES);       // 8.0 MB
  int* bucket_cursor = (int*)(pairs + (size_t)NB2 * MAXB2);  // 782*16

  hipMemsetAsync(bucket_cursor, 0, NB2 * CUR_STRIDE * sizeof(int), stream);
  fat1_kernel<<<PROJ_BLKS, 512, 0, stream>>>(h_init, W1, a, h16, ha);
  bin_scatter_kernel<<<BIN_NBLK, BIN_THREADS, 0, stream>>>(src, dst,
                                                           bucket_cursor,
                                                           pairs);
  sortgather_kernel<<<NB2, SG_THREADS, 0, stream>>>(h16, ha, bucket_cursor,
                                                    pairs, out);
}

// Round 13
// 186.460 us; speedup vs baseline: 1.0287x; 1.0287x over previous
//
#include <hip/hip_runtime.h>
#include <hip/hip_fp16.h>

#define N_NODES 100000
#define N_EDGES 1600000
#define IN_DIM 128
#define OUT_DIM 64

#define PROJ_BLKS 782  // ceil(N_NODES/128): 128 rows per block (8 waves x 16)

// Buckets of 128 nodes: bucket = dst >> 7.
#define NB2 782        // ceil(N_NODES/128)
#define MAXB2 2560     // Binom(1.6M,128/1e5): mean 2048, sigma 45; +11 sigma
#define CUR_STRIDE 16  // one cursor per 64B line (no cross-XCD false sharing)

#define BIN_NBLK 500
#define BIN_CHUNK 3200    // BIN_NBLK * BIN_CHUNK == N_EDGES
#define BIN_THREADS 1024  // ~2 blocks/CU (was <1/CU at 250 blocks)

#define SG_THREADS 512  // 8 waves; ~33KB LDS -> 4 blocks/CU

typedef short short8 __attribute__((ext_vector_type(8)));
typedef float f32x4 __attribute__((ext_vector_type(4)));

__device__ __forceinline__ short bf16_trunc(float x) {
  return (short)(__float_as_uint(x) >> 16);
}
__device__ __forceinline__ float bf16_tof(short s) {
  return __uint_as_float(((unsigned)(unsigned short)s) << 16);
}
__device__ __forceinline__ float edge_ex(float p) {
  float t2 = __expf(2.f * p);
  float th = 1.f - 2.f * __builtin_amdgcn_rcpf(t2 + 1.f);
  return __expf(th);
}

// ---------------- Kernel 1: MFMA projection (R10-verified) ----------------
__global__ __launch_bounds__(512) void fat1_kernel(
    const float* __restrict__ h_init, const float* __restrict__ W1,
    const float* __restrict__ a, __half* __restrict__ h16,
    float* __restrict__ ha) {
  __shared__ short whi[16 * 64 * 8];  // 16 KB
  __shared__ short wlo[16 * 64 * 8];  // 16 KB
  int t = threadIdx.x;

  // stage W as bf16 hi/lo B-fragments (frag f=kc*4+ot, B[k][n]=W1[ot*16+n][k])
  for (int idx = t; idx < 16 * 64; idx += 512) {
    int f = idx >> 6;
    int l = idx & 63;
    int kc = f >> 2, ot = f & 3;
    const float* wsrc =
        W1 + (ot * 16 + (l & 15)) * IN_DIM + kc * 32 + (l >> 4) * 8;
    short hi[8], lo[8];
#pragma unroll
    for (int j = 0; j < 8; j++) {
      float x = wsrc[j];
      short hv = bf16_trunc(x);
      hi[j] = hv;
      lo[j] = bf16_trunc(x - bf16_tof(hv));
    }
    *(short8*)&whi[idx * 8] = *(const short8*)hi;
    *(short8*)&wlo[idx * 8] = *(const short8*)lo;
  }

  int row0 = blockIdx.x * 128;
  int w = t >> 6;  // wave 0..7, 16 rows each
  int l = t & 63;
  int m = l & 15;
  int q = l >> 4;

  int arow = row0 + w * 16 + m;
  if (arow >= N_NODES) arow = N_NODES - 1;
  const float* xsrc = h_init + (size_t)arow * IN_DIM + q * 8;

  short8 ahi[4], alo[4];
#pragma unroll
  for (int kc = 0; kc < 4; kc++) {
    float xv[8];
    *(float4*)&xv[0] = *(const float4*)(xsrc + kc * 32);
    *(float4*)&xv[4] = *(const float4*)(xsrc + kc * 32 + 4);
    short hi[8], lo[8];
#pragma unroll
    for (int j = 0; j < 8; j++) {
      short hv = bf16_trunc(xv[j]);
      hi[j] = hv;
      lo[j] = bf16_trunc(xv[j] - bf16_tof(hv));
    }
    ahi[kc] = *(const short8*)hi;
    alo[kc] = *(const short8*)lo;
  }
  __syncthreads();

  f32x4 acc[4] = {{0.f, 0.f, 0.f, 0.f},
                  {0.f, 0.f, 0.f, 0.f},
                  {0.f, 0.f, 0.f, 0.f},
                  {0.f, 0.f, 0.f, 0.f}};

#pragma unroll
  for (int kc = 0; kc < 4; kc++) {
#pragma unroll
    for (int ot = 0; ot < 4; ot++) {
      int base = (((kc << 2) | ot) * 64 + l) * 8;
      short8 bhi = *(const short8*)&whi[base];
      short8 blo = *(const short8*)&wlo[base];
      acc[ot] = __builtin_amdgcn_mfma_f32_16x16x32_bf16(ahi[kc], bhi, acc[ot],
                                                        0, 0, 0);
      acc[ot] = __builtin_amdgcn_mfma_f32_16x16x32_bf16(ahi[kc], blo, acc[ot],
                                                        0, 0, 0);
      acc[ot] = __builtin_amdgcn_mfma_f32_16x16x32_bf16(alo[kc], bhi, acc[ot],
                                                        0, 0, 0);
    }
  }

  float pa[4] = {0.f, 0.f, 0.f, 0.f};
#pragma unroll
  for (int ot = 0; ot < 4; ot++) {
    float aval = a[ot * 16 + m];
#pragma unroll
    for (int r = 0; r < 4; r++) pa[r] += acc[ot][r] * aval;
  }
  int rowb = row0 + w * 16 + q * 4;
#pragma unroll
  for (int r = 0; r < 4; r++) {
    int row = rowb + r;
    if (row < N_NODES) {
#pragma unroll
      for (int ot = 0; ot < 4; ot++)
        h16[(size_t)row * OUT_DIM + ot * 16 + m] = __float2half(acc[ot][r]);
    }
  }
#pragma unroll
  for (int r = 0; r < 4; r++) {
    pa[r] += __shfl_xor(pa[r], 1);
    pa[r] += __shfl_xor(pa[r], 2);
    pa[r] += __shfl_xor(pa[r], 4);
    pa[r] += __shfl_xor(pa[r], 8);
  }
  if (m == 0) {
#pragma unroll
    for (int r = 0; r < 4; r++) {
      int row = rowb + r;
      if (row < N_NODES) ha[row] = pa[r];
    }
  }
}

// ------- Partition into static 128-node bucket regions (R5/R8 structure) ---
// 500 blocks (~2/CU): 2x TLP on the latency chains vs 250 (<1/CU).
__global__ __launch_bounds__(BIN_THREADS) void bin_scatter_kernel(
    const int* __restrict__ src, const int* __restrict__ dst,
    int* __restrict__ bucket_cursor, unsigned int* __restrict__ pairs) {
  __shared__ int hst[NB2];
  __shared__ int cur[NB2];
  __shared__ int dlds[BIN_CHUNK];  // 12.8 KB dst cache
  int t = threadIdx.x;
  for (int i = t; i < NB2; i += BIN_THREADS) hst[i] = 0;
  __syncthreads();
  int beg = blockIdx.x * BIN_CHUNK;
  for (int e = t; e < BIN_CHUNK; e += BIN_THREADS) {
    int d = dst[beg + e];
    dlds[e] = d;
    atomicAdd(&hst[d >> 7], 1);
  }
  __syncthreads();
  for (int i = t; i < NB2; i += BIN_THREADS) {
    int c = hst[i];
    cur[i] =
        (c > 0) ? atomicAdd(&bucket_cursor[i * CUR_STRIDE], c) + i * MAXB2 : 0;
  }
  __syncthreads();
  for (int e = t; e < BIN_CHUNK; e += BIN_THREADS) {
    int d = dlds[e];
    int pos = atomicAdd(&cur[d >> 7], 1);
    pairs[pos] = ((unsigned int)src[beg + e] << 7) | (unsigned int)(d & 127);
  }
}

// ---- Fused sort+gather: in-LDS counting sort, then SUBGROUP-PER-NODE ------
// Byte-identical to the R10-verified body (43 µs, VGPR 32, occupancy 41%):
// 4-deep gather MLP; simple ex-scatter. R11 measured that deeper MLP costs
// VGPR -> occupancy (41->27%) and regresses; this is the equilibrium point.
__global__ __launch_bounds__(SG_THREADS) void sortgather_kernel(
    const __half* __restrict__ h16, const float* __restrict__ ha,
    const int* __restrict__ bucket_cursor,
    const unsigned int* __restrict__ pairs, float* __restrict__ out) {
  __shared__ unsigned int plds[MAXB2];  // 10.2 KB
  __shared__ int2 slds[MAXB2];          // 20.5 KB
  __shared__ float had[128];
  __shared__ int hist[128];
  __shared__ int scn[128];
  __shared__ int cur[128];
  __shared__ int wsum;
  int b = blockIdx.x;
  int t = threadIdx.x;
  int node0 = b << 7;
  int cnt = min(bucket_cursor[b * CUR_STRIDE], MAXB2);

  if (t < 128) {
    int node = node0 + t;
    had[t] = (node < N_NODES) ? ha[node] : 0.f;
    hist[t] = 0;
  }
  __syncthreads();
  // ingest: uint4 (4 edges/load), scalar tail
  int c4 = cnt & ~3;
  for (int i = t * 4; i < c4; i += SG_THREADS * 4) {
    uint4 p4 = *(const uint4*)&pairs[(size_t)b * MAXB2 + i];
    *(uint4*)&plds[i] = p4;
    atomicAdd(&hist[p4.x & 127u], 1);
    atomicAdd(&hist[p4.y & 127u], 1);
    atomicAdd(&hist[p4.z & 127u], 1);
    atomicAdd(&hist[p4.w & 127u], 1);
  }
  for (int i = c4 + t; i < cnt; i += SG_THREADS) {
    unsigned int p = pairs[(size_t)b * MAXB2 + i];
    plds[i] = p;
    atomicAdd(&hist[p & 127u], 1);
  }
  __syncthreads();
  // 2-wave shfl inclusive scan over hist[0..127]
  int v = (t < 128) ? hist[t] : 0;
  int x = v;
#pragma unroll
  for (int off = 1; off < 64; off <<= 1) {
    int y = __shfl_up(x, off, 64);
    if ((t & 63) >= off) x += y;
  }
  if (t == 63) wsum = x;
  __syncthreads();
  if (t >= 64 && t < 128) x += wsum;
  if (t < 128) {
    scn[t] = x;
    cur[t] = x - v;  // exclusive prefix
  }
  __syncthreads();
  for (int i = t; i < cnt; i += SG_THREADS) {
    unsigned int p = plds[i];
    int nl = (int)(p & 127u);
    int sb = (int)(p & 0xFFFFFF80u);  // src << 7 == h16 row byte offset
    float ex = edge_ex(had[nl] - ha[sb >> 7]);
    int pos = atomicAdd(&cur[nl], 1);
    slds[pos] = make_int2(sb, __float_as_int(ex));
  }
  __syncthreads();

  // ---- gather: subgroup sg (8 lanes) owns nodes sg, sg+64 (R10-verified) --
  int sg = t >> 3;  // subgroup 0..63
  int l8 = t & 7;   // cols [8*l8, 8*l8+8)
  const char* h16b = (const char*)h16;
  float4* o4 = (float4*)out;

  for (int nl = sg; nl < 128; nl += 64) {
    int node = node0 + nl;
    if (node >= N_NODES) continue;  // only trims the last bucket
    int endp = scn[nl];
    int begp = endp - hist[nl];
    union {
      uint4 u;
      __half hh[8];
    } HD;
    HD.u = *(const uint4*)(h16b + ((size_t)node << 7) + (l8 << 4));
    float acc[8] = {0.f, 0.f, 0.f, 0.f, 0.f, 0.f, 0.f, 0.f};
    float den = 0.f;
    int last = endp - 1;

    for (int base = begp; base < endp; base += 4) {  // 4 edges in flight
      int2 e[4];
      float exv[4];
#pragma unroll
      for (int k = 0; k < 4; k++) {
        int i = base + k;
        e[k] = slds[i < endp ? i : last];
        exv[k] = (i < endp) ? __int_as_float(e[k].y) : 0.f;
      }
      uint4 uv[4];
#pragma unroll
      for (int k = 0; k < 4; k++)
        uv[k] = *(const uint4*)(h16b + e[k].x + (l8 << 4));
#pragma unroll
      for (int k = 0; k < 4; k++) {
        union {
          uint4 u;
          __half hh[8];
        } U;
        U.u = uv[k];
        float ex = exv[k];
        den += ex;
#pragma unroll
        for (int j = 0; j < 8; j++)
          acc[j] = fmaf(__half2float(U.hh[j]), ex, acc[j]);  // v_fma_mix_f32
      }
    }

    bool has = den > 0.f;
    float inv = has ? __builtin_amdgcn_rcpf(den) : 0.f;
    float hd[8];
#pragma unroll
    for (int j = 0; j < 8; j++) hd[j] = __half2float(HD.hh[j]);
    float4 r0, r1;
    r0.x = fmaxf(has ? 2.f * hd[0] - acc[0] * inv : hd[0], 0.f);
    r0.y = fmaxf(has ? 2.f * hd[1] - acc[1] * inv : hd[1], 0.f);
    r0.z = fmaxf(has ? 2.f * hd[2] - acc[2] * inv : hd[2], 0.f);
    r0.w = fmaxf(has ? 2.f * hd[3] - acc[3] * inv : hd[3], 0.f);
    r1.x = fmaxf(has ? 2.f * hd[4] - acc[4] * inv : hd[4], 0.f);
    r1.y = fmaxf(has ? 2.f * hd[5] - acc[5] * inv : hd[5], 0.f);
    r1.z = fmaxf(has ? 2.f * hd[6] - acc[6] * inv : hd[6], 0.f);
    r1.w = fmaxf(has ? 2.f * hd[7] - acc[7] * inv : hd[7], 0.f);
    o4[(size_t)node * (OUT_DIM / 4) + l8 * 2] = r0;
    o4[(size_t)node * (OUT_DIM / 4) + l8 * 2 + 1] = r1;
  }
}

extern "C" void kernel_launch(void* const* d_in, const int* in_sizes, int n_in,
                              void* d_out, int out_size, void* d_ws,
                              size_t ws_size, hipStream_t stream) {
  const float* h_init = (const float*)d_in[0];
  const float* W1 = (const float*)d_in[1];
  const float* a = (const float*)d_in[2];
  const int* src = (const int*)d_in[3];
  const int* dst = (const int*)d_in[4];
  float* out = (float*)d_out;

  // workspace layout (~22 MB)
  __half* h16 = (__half*)d_ws;                               // 12.8 MB
  float* ha = (float*)(h16 + (size_t)N_NODES * OUT_DIM);     // 0.4 MB
  unsigned int* pairs = (unsigned int*)(ha + N_NODES);       // 8.0 MB
  int* bucket_cursor = (int*)(pairs + (size_t)NB2 * MAXB2);  // 782*16

  hipMemsetAsync(bucket_cursor, 0, NB2 * CUR_STRIDE * sizeof(int), stream);
  fat1_kernel<<<PROJ_BLKS, 512, 0, stream>>>(h_init, W1, a, h16, ha);
  bin_scatter_kernel<<<BIN_NBLK, BIN_THREADS, 0, stream>>>(src, dst,
                                                           bucket_cursor,
                                                           pairs);
  sortgather_kernel<<<NB2, SG_THREADS, 0, stream>>>(h16, ha, bucket_cursor,
                                                    pairs, out);
}

// Round 14
// 173.285 us; speedup vs baseline: 1.1069x; 1.0760x over previous
//
#include <hip/hip_runtime.h>
#include <hip/hip_fp16.h>

#define N_NODES 100000
#define N_EDGES 1600000
#define IN_DIM 128
#define OUT_DIM 64

#define PROJ_BLKS 782  // ceil(N_NODES/128): 128 rows per block (8 waves x 16)

// Buckets of 128 nodes: bucket = dst >> 7.
#define NB2 782        // ceil(N_NODES/128)
#define MAXB2 2560     // Binom(1.6M,128/1e5): mean 2048, sigma 45; +11 sigma
#define CUR_STRIDE 16  // one cursor per 64B line (no cross-XCD false sharing)

#define BIN_NBLK 250
#define BIN_CHUNK 6400    // BIN_NBLK * BIN_CHUNK == N_EDGES; runs ~8 edges
#define BIN_THREADS 1024

#define SG_THREADS 512  // 8 waves; ~33KB LDS -> 4 blocks/CU

typedef short short8 __attribute__((ext_vector_type(8)));
typedef float f32x4 __attribute__((ext_vector_type(4)));

__device__ __forceinline__ short bf16_trunc(float x) {
  return (short)(__float_as_uint(x) >> 16);
}
__device__ __forceinline__ float bf16_tof(short s) {
  return __uint_as_float(((unsigned)(unsigned short)s) << 16);
}
__device__ __forceinline__ float edge_ex(float p) {
  float t2 = __expf(2.f * p);
  float th = 1.f - 2.f * __builtin_amdgcn_rcpf(t2 + 1.f);
  return __expf(th);
}

// ---------------- Kernel 1: MFMA projection (R10-verified) ----------------
__global__ __launch_bounds__(512) void fat1_kernel(
    const float* __restrict__ h_init, const float* __restrict__ W1,
    const float* __restrict__ a, __half* __restrict__ h16,
    float* __restrict__ ha) {
  __shared__ short whi[16 * 64 * 8];  // 16 KB
  __shared__ short wlo[16 * 64 * 8];  // 16 KB
  int t = threadIdx.x;

  // stage W as bf16 hi/lo B-fragments (frag f=kc*4+ot, B[k][n]=W1[ot*16+n][k])
  for (int idx = t; idx < 16 * 64; idx += 512) {
    int f = idx >> 6;
    int l = idx & 63;
    int kc = f >> 2, ot = f & 3;
    const float* wsrc =
        W1 + (ot * 16 + (l & 15)) * IN_DIM + kc * 32 + (l >> 4) * 8;
    short hi[8], lo[8];
#pragma unroll
    for (int j = 0; j < 8; j++) {
      float x = wsrc[j];
      short hv = bf16_trunc(x);
      hi[j] = hv;
      lo[j] = bf16_trunc(x - bf16_tof(hv));
    }
    *(short8*)&whi[idx * 8] = *(const short8*)hi;
    *(short8*)&wlo[idx * 8] = *(const short8*)lo;
  }

  int row0 = blockIdx.x * 128;
  int w = t >> 6;  // wave 0..7, 16 rows each
  int l = t & 63;
  int m = l & 15;
  int q = l >> 4;

  int arow = row0 + w * 16 + m;
  if (arow >= N_NODES) arow = N_NODES - 1;
  const float* xsrc = h_init + (size_t)arow * IN_DIM + q * 8;

  short8 ahi[4], alo[4];
#pragma unroll
  for (int kc = 0; kc < 4; kc++) {
    float xv[8];
    *(float4*)&xv[0] = *(const float4*)(xsrc + kc * 32);
    *(float4*)&xv[4] = *(const float4*)(xsrc + kc * 32 + 4);
    short hi[8], lo[8];
#pragma unroll
    for (int j = 0; j < 8; j++) {
      short hv = bf16_trunc(xv[j]);
      hi[j] = hv;
      lo[j] = bf16_trunc(xv[j] - bf16_tof(hv));
    }
    ahi[kc] = *(const short8*)hi;
    alo[kc] = *(const short8*)lo;
  }
  __syncthreads();

  f32x4 acc[4] = {{0.f, 0.f, 0.f, 0.f},
                  {0.f, 0.f, 0.f, 0.f},
                  {0.f, 0.f, 0.f, 0.f},
                  {0.f, 0.f, 0.f, 0.f}};

#pragma unroll
  for (int kc = 0; kc < 4; kc++) {
#pragma unroll
    for (int ot = 0; ot < 4; ot++) {
      int base = (((kc << 2) | ot) * 64 + l) * 8;
      short8 bhi = *(const short8*)&whi[base];
      short8 blo = *(const short8*)&wlo[base];
      acc[ot] = __builtin_amdgcn_mfma_f32_16x16x32_bf16(ahi[kc], bhi, acc[ot],
                                                        0, 0, 0);
      acc[ot] = __builtin_amdgcn_mfma_f32_16x16x32_bf16(ahi[kc], blo, acc[ot],
                                                        0, 0, 0);
      acc[ot] = __builtin_amdgcn_mfma_f32_16x16x32_bf16(alo[kc], bhi, acc[ot],
                                                        0, 0, 0);
    }
  }

  float pa[4] = {0.f, 0.f, 0.f, 0.f};
#pragma unroll
  for (int ot = 0; ot < 4; ot++) {
    float aval = a[ot * 16 + m];
#pragma unroll
    for (int r = 0; r < 4; r++) pa[r] += acc[ot][r] * aval;
  }
  int rowb = row0 + w * 16 + q * 4;
#pragma unroll
  for (int r = 0; r < 4; r++) {
    int row = rowb + r;
    if (row < N_NODES) {
#pragma unroll
      for (int ot = 0; ot < 4; ot++)
        h16[(size_t)row * OUT_DIM + ot * 16 + m] = __float2half(acc[ot][r]);
    }
  }
#pragma unroll
  for (int r = 0; r < 4; r++) {
    pa[r] += __shfl_xor(pa[r], 1);
    pa[r] += __shfl_xor(pa[r], 2);
    pa[r] += __shfl_xor(pa[r], 4);
    pa[r] += __shfl_xor(pa[r], 8);
  }
  if (m == 0) {
#pragma unroll
    for (int r = 0; r < 4; r++) {
      int row = rowb + r;
      if (row < N_NODES) ha[row] = pa[r];
    }
  }
}

// ------- Bin with in-LDS chunk sort: COALESCED pairs writes ----------------
// R13 measured the old per-edge scattered write at 44.5 µs, WRITE 35.5MB
// (write-transaction-bound: 64 scattered 4B stores per wave). Here the chunk
// is counting-sorted in LDS first, so pass C writes consecutive addresses:
// a wave's 64 u32s span ~8 bucket runs -> ~8 transactions instead of 64.
__global__ __launch_bounds__(BIN_THREADS) void bin_scatter_kernel(
    const int* __restrict__ src, const int* __restrict__ dst,
    int* __restrict__ bucket_cursor, unsigned int* __restrict__ pairs) {
  __shared__ unsigned int slds[BIN_CHUNK];  // 25.6 KB sorted pairs
  __shared__ int gofs[BIN_CHUNK];           // 25.6 KB per-slot global base
  __shared__ int hist[NB2];
  __shared__ int lcur[NB2];
  __shared__ int gbase[NB2];
  __shared__ int wsum[16];
  int t = threadIdx.x;
  int lane = t & 63;
  int wid = t >> 6;
  int beg = blockIdx.x * BIN_CHUNK;

  for (int i = t; i < NB2; i += BIN_THREADS) hist[i] = 0;
  __syncthreads();
  // Pass A: histogram
  for (int e = beg + t; e < beg + BIN_CHUNK; e += BIN_THREADS)
    atomicAdd(&hist[dst[e] >> 7], 1);
  __syncthreads();
  // 782-entry two-level inclusive scan (16 waves of 64)
  int v = (t < NB2) ? hist[t] : 0;
  int x = v;
#pragma unroll
  for (int off = 1; off < 64; off <<= 1) {
    int y = __shfl_up(x, off, 64);
    if (lane >= off) x += y;
  }
  if (lane == 63) wsum[wid] = x;
  __syncthreads();
  if (t < 16) {
    int s = wsum[t];
#pragma unroll
    for (int off = 1; off < 16; off <<= 1) {
      int y = __shfl_up(s, off, 16);
      if (t >= off) s += y;
    }
    wsum[t] = s;
  }
  __syncthreads();
  if (wid > 0) x += wsum[wid - 1];
  int lpos = x - v;  // exclusive local prefix
  if (t < NB2) {
    int g = (v > 0) ? atomicAdd(&bucket_cursor[t * CUR_STRIDE], v) : 0;
    gbase[t] = g + t * MAXB2 - lpos;  // gaddr = gbase[b] + sorted_slot
    lcur[t] = lpos;
  }
  __syncthreads();
  // Pass B: scatter into LDS sorted order (dst/src re-read, L2-warm)
  for (int e = beg + t; e < beg + BIN_CHUNK; e += BIN_THREADS) {
    int d = dst[e];
    int s = src[e];
    int b_ = d >> 7;
    int li = atomicAdd(&lcur[b_], 1);
    slds[li] = ((unsigned)s << 7) | (unsigned)(d & 127);
    gofs[li] = gbase[b_];
  }
  __syncthreads();
  // Pass C: coalesced global write
  for (int j = t; j < BIN_CHUNK; j += BIN_THREADS)
    pairs[gofs[j] + j] = slds[j];
}

// ---- Fused sort+gather: in-LDS counting sort, then SUBGROUP-PER-NODE ------
// Byte-identical to the R10-verified body (43 µs, VGPR 32, occupancy 41%).
__global__ __launch_bounds__(SG_THREADS) void sortgather_kernel(
    const __half* __restrict__ h16, const float* __restrict__ ha,
    const int* __restrict__ bucket_cursor,
    const unsigned int* __restrict__ pairs, float* __restrict__ out) {
  __shared__ unsigned int plds[MAXB2];  // 10.2 KB
  __shared__ int2 slds[MAXB2];          // 20.5 KB
  __shared__ float had[128];
  __shared__ int hist[128];
  __shared__ int scn[128];
  __shared__ int cur[128];
  __shared__ int wsum;
  int b = blockIdx.x;
  int t = threadIdx.x;
  int node0 = b << 7;
  int cnt = min(bucket_cursor[b * CUR_STRIDE], MAXB2);

  if (t < 128) {
    int node = node0 + t;
    had[t] = (node < N_NODES) ? ha[node] : 0.f;
    hist[t] = 0;
  }
  __syncthreads();
  // ingest: uint4 (4 edges/load), scalar tail
  int c4 = cnt & ~3;
  for (int i = t * 4; i < c4; i += SG_THREADS * 4) {
    uint4 p4 = *(const uint4*)&pairs[(size_t)b * MAXB2 + i];
    *(uint4*)&plds[i] = p4;
    atomicAdd(&hist[p4.x & 127u], 1);
    atomicAdd(&hist[p4.y & 127u], 1);
    atomicAdd(&hist[p4.z & 127u], 1);
    atomicAdd(&hist[p4.w & 127u], 1);
  }
  for (int i = c4 + t; i < cnt; i += SG_THREADS) {
    unsigned int p = pairs[(size_t)b * MAXB2 + i];
    plds[i] = p;
    atomicAdd(&hist[p & 127u], 1);
  }
  __syncthreads();
  // 2-wave shfl inclusive scan over hist[0..127]
  int v = (t < 128) ? hist[t] : 0;
  int x = v;
#pragma unroll
  for (int off = 1; off < 64; off <<= 1) {
    int y = __shfl_up(x, off, 64);
    if ((t & 63) >= off) x += y;
  }
  if (t == 63) wsum = x;
  __syncthreads();
  if (t >= 64 && t < 128) x += wsum;
  if (t < 128) {
    scn[t] = x;
    cur[t] = x - v;  // exclusive prefix
  }
  __syncthreads();
  for (int i = t; i < cnt; i += SG_THREADS) {
    unsigned int p = plds[i];
    int nl = (int)(p & 127u);
    int sb = (int)(p & 0xFFFFFF80u);  // src << 7 == h16 row byte offset
    float ex = edge_ex(had[nl] - ha[sb >> 7]);
    int pos = atomicAdd(&cur[nl], 1);
    slds[pos] = make_int2(sb, __float_as_int(ex));
  }
  __syncthreads();

  // ---- gather: subgroup sg (8 lanes) owns nodes sg, sg+64 (R10-verified) --
  int sg = t >> 3;  // subgroup 0..63
  int l8 = t & 7;   // cols [8*l8, 8*l8+8)
  const char* h16b = (const char*)h16;
  float4* o4 = (float4*)out;

  for (int nl = sg; nl < 128; nl += 64) {
    int node = node0 + nl;
    if (node >= N_NODES) continue;  // only trims the last bucket
    int endp = scn[nl];
    int begp = endp - hist[nl];
    union {
      uint4 u;
      __half hh[8];
    } HD;
    HD.u = *(const uint4*)(h16b + ((size_t)node << 7) + (l8 << 4));
    float acc[8] = {0.f, 0.f, 0.f, 0.f, 0.f, 0.f, 0.f, 0.f};
    float den = 0.f;
    int last = endp - 1;

    for (int base = begp; base < endp; base += 4) {  // 4 edges in flight
      int2 e[4];
      float exv[4];
#pragma unroll
      for (int k = 0; k < 4; k++) {
        int i = base + k;
        e[k] = slds[i < endp ? i : last];
        exv[k] = (i < endp) ? __int_as_float(e[k].y) : 0.f;
      }
      uint4 uv[4];
#pragma unroll
      for (int k = 0; k < 4; k++)
        uv[k] = *(const uint4*)(h16b + e[k].x + (l8 << 4));
#pragma unroll
      for (int k = 0; k < 4; k++) {
        union {
          uint4 u;
          __half hh[8];
        } U;
        U.u = uv[k];
        float ex = exv[k];
        den += ex;
#pragma unroll
        for (int j = 0; j < 8; j++)
          acc[j] = fmaf(__half2float(U.hh[j]), ex, acc[j]);  // v_fma_mix_f32
      }
    }

    bool has = den > 0.f;
    float inv = has ? __builtin_amdgcn_rcpf(den) : 0.f;
    float hd[8];
#pragma unroll
    for (int j = 0; j < 8; j++) hd[j] = __half2float(HD.hh[j]);
    float4 r0, r1;
    r0.x = fmaxf(has ? 2.f * hd[0] - acc[0] * inv : hd[0], 0.f);
    r0.y = fmaxf(has ? 2.f * hd[1] - acc[1] * inv : hd[1], 0.f);
    r0.z = fmaxf(has ? 2.f * hd[2] - acc[2] * inv : hd[2], 0.f);
    r0.w = fmaxf(has ? 2.f * hd[3] - acc[3] * inv : hd[3], 0.f);
    r1.x = fmaxf(has ? 2.f * hd[4] - acc[4] * inv : hd[4], 0.f);
    r1.y = fmaxf(has ? 2.f * hd[5] - acc[5] * inv : hd[5], 0.f);
    r1.z = fmaxf(has ? 2.f * hd[6] - acc[6] * inv : hd[6], 0.f);
    r1.w = fmaxf(has ? 2.f * hd[7] - acc[7] * inv : hd[7], 0.f);
    o4[(size_t)node * (OUT_DIM / 4) + l8 * 2] = r0;
    o4[(size_t)node * (OUT_DIM / 4) + l8 * 2 + 1] = r1;
  }
}

extern "C" void kernel_launch(void* const* d_in, const int* in_sizes, int n_in,
                              void* d_out, int out_size, void* d_ws,
                              size_t ws_size, hipStream_t stream) {
  const float* h_init = (const float*)d_in[0];
  const float* W1 = (const float*)d_in[1];
  const float* a = (const float*)d_in[2];
  const int* src = (const int*)d_in[3];
  const int* dst = (const int*)d_in[4];
  float* out = (float*)d_out;

  // workspace layout (~22 MB)
  __half* h16 = (__half*)d_ws;                               // 12.8 MB
  float* ha = (float*)(h16 + (size_t)N_NODES * OUT_DIM);     // 0.4 MB
  unsigned int* pairs = (unsigned int*)(ha + N_NODES);       // 8.0 MB
  int* bucket_cursor = (int*)(pairs + (size_t)NB2 * MAXB2);  // 782*16

  hipMemsetAsync(bucket_cursor, 0, NB2 * CUR_STRIDE * sizeof(int), stream);
  fat1_kernel<<<PROJ_BLKS, 512, 0, stream>>>(h_init, W1, a, h16, ha);
  bin_scatter_kernel<<<BIN_NBLK, BIN_THREADS, 0, stream>>>(src, dst,
                                                           bucket_cursor,
                                                           pairs);
  sortgather_kernel<<<NB2, SG_THREADS, 0, stream>>>(h16, ha, bucket_cursor,
                                                    pairs, out);
}